// Round 10
// baseline (60.167 us; speedup 1.0000x reference)
//
#include <hip/hip_runtime.h>

// ROIAlign3D: features [B=2,C=128,D=16,H=64,W=64] f32, rois [B,N=64,6] f32
// out [B,N,C,7,7,7] f32. SAMPLING_RATIO=2, ALIGNED=true, SPATIAL_SCALE=1.
//
// Round 10: v9 cell phase unchanged (z 3-slot collapse, fdot2, perms).
// Staging restructured:
//  - 4-voxel chunks (rows x 6 main, x=24 tail loop): index math amortized 4x,
//    stores fuse to ds_write2_b32.
//  - magic-div row->(z,y) (m = 65535/yn+1, exact for row<=250): no rowglob
//    table, no LDS reads in staging.
//  - single barrier: staging depends on no LDS -> global loads issue
//    immediately; tables ready by the one barrier.
constexpr int Bc = 2, Nc = 64, Cc = 128, Dc = 16, Hc = 64, Wc = 64;
constexpr int OD = 7, OH = 7, OW = 7;
constexpr int CELLS = OD * OH * OW;          // 343
constexpr int DHW = Dc * Hc * Wc, HW = Hc * Wc;
constexpr int MAXZ = 10, MAXY = 25, MAXX = 25;
constexpr int XS = 25;                        // fixed x stride in LDS
constexpr int SUBSZ = MAXZ * MAXY * XS;       // 6250

typedef __fp16 h2 __attribute__((ext_vector_type(2)));

__device__ inline unsigned pk_f16(float a, float b) {
    return __builtin_bit_cast(unsigned, __builtin_amdgcn_cvt_pkrtz(a, b));
}

__device__ inline float fdot2(unsigned a, unsigned b, float c) {
#if __has_builtin(__builtin_amdgcn_fdot2)
    return __builtin_amdgcn_fdot2(__builtin_bit_cast(h2, a),
                                  __builtin_bit_cast(h2, b), c, false);
#else
    h2 ha = __builtin_bit_cast(h2, a);
    h2 hb = __builtin_bit_cast(h2, b);
    return fmaf((float)ha.x, (float)hb.x, fmaf((float)ha.y, (float)hb.y, c));
#endif
}

__global__ __launch_bounds__(384) void roialign3d_v10(
    const float* __restrict__ feat, const float* __restrict__ rois,
    float* __restrict__ out)
{
    __shared__ unsigned sub[SUBSZ + 2];       // [0]=front pad, data, end pad
    __shared__ int2     tzp[14], typ[14];     // tzp: RAW z rows (c0,c1)
    __shared__ float2   wzp[14], wyp[14];
    __shared__ int      txo[14];
    __shared__ unsigned wxh[14];              // packed f16 (w_left, w_right)

    const int blk = blockIdx.x;
    const int cp  = blk & 63;
    const int n   = (blk >> 6) & 63;
    const int b   = blk >> 12;
    const int tid = threadIdx.x;

    const float* rp = rois + (size_t)(b * Nc + n) * 6;
    float r1a[3] = {rp[0] - 0.5f, rp[1] - 0.5f, rp[2] - 0.5f};
    float r2a[3] = {rp[3] - 0.5f, rp[4] - 0.5f, rp[5] - 0.5f};
    const int dims[3] = {Dc, Hc, Wc};
    const int maxn[3] = {MAXZ, MAXY, MAXX};

    float bs[3]; int lo[3], ncnt[3];
    #pragma unroll
    for (int a = 0; a < 3; ++a) {
        bs[a] = fmaxf(r2a[a] - r1a[a], 1e-6f) * (1.0f / 7.0f);
        float smin = r1a[a] + 0.25f * bs[a];
        float smax = r1a[a] + 6.75f * bs[a];
        int l = max(0, (int)floorf(smin));
        int h = min(dims[a] - 1, (int)floorf(smax) + 1);
        lo[a] = l;
        ncnt[a] = min(h - l + 1, maxn[a]);    // maxn clamp = memory safety only
    }
    const int zn = ncnt[0], yn = ncnt[1], xn = ncnt[2];
    const int rows = zn * yn;
    const int zstride = yn * XS;

    // Axis tables (42 threads).
    if (tid < 42) {
        int a = tid / 14, m = tid - a * 14;
        float v = r1a[a] + ((float)m + 0.5f) * 0.5f * bs[a];
        float f = floorf(v);
        float l = v - f;
        int i0 = (int)f;
        int d  = dims[a];
        float w0 = (i0 >= 0 && i0 < d) ? 1.0f - l : 0.0f;
        float w1 = (i0 + 1 < d) ? l : 0.0f;
        if (a == 0) {
            int c0 = min(max(i0 - lo[0], 0), zn - 1);
            int c1 = min(max(i0 + 1 - lo[0], 0), zn - 1);
            tzp[m] = make_int2(c0, c1);              // RAW rows
            wzp[m] = make_float2(w0, w1);
        } else if (a == 1) {
            int c0 = min(max(i0 - lo[1], 0), yn - 1);
            int c1 = min(max(i0 + 1 - lo[1], 0), yn - 1);
            typ[m] = make_int2(c0 * XS, c1 * XS);
            wyp[m] = make_float2(w0, w1);
        } else {
            // pair trick: corners are (c0, c0+1); c0 in [-1, xn-1].
            int c0 = min(max(i0 - lo[2], -1), xn - 1);
            txo[m] = c0;
            wxh[m] = pk_f16(w0, w1);
        }
    }
    if (tid == 64) sub[0] = 0;                       // front pad (x pair at -1)
    if (tid == 65) sub[1 + rows * XS] = 0;           // element after staged data

    // ---- Stage subvolume (fp16x2 interleaved), no LDS dependencies. ----
    const int c0ch = cp * 2;
    const float* fb = feat + ((size_t)b * Cc + c0ch) * DHW;
    const unsigned mz = 65535u / (unsigned)yn + 1u;  // = ceil(65536/yn)
    const int gz = lo[0] * HW + lo[1] * Wc + lo[2];

    // main: rows x 6 full 4-voxel chunks (x0 = 0..20)
    const int nmain = rows * 6;
    for (int p = tid; p < nmain; p += 384) {
        int row = (p * 10923) >> 16;                 // p/6, exact for p<1500
        int c   = p - row * 6;
        int x0  = c << 2;
        int z   = (int)(((unsigned)row * mz) >> 16); // row/yn
        int y   = row - z * yn;
        int g   = gz + z * HW + y * Wc;
        int xs0 = min(x0,     xn - 1);
        int xs1 = min(x0 + 1, xn - 1);
        int xs2 = min(x0 + 2, xn - 1);
        int xs3 = min(x0 + 3, xn - 1);
        unsigned d0 = pk_f16(fb[g + xs0], fb[g + xs0 + DHW]);
        unsigned d1 = pk_f16(fb[g + xs1], fb[g + xs1 + DHW]);
        unsigned d2 = pk_f16(fb[g + xs2], fb[g + xs2 + DHW]);
        unsigned d3 = pk_f16(fb[g + xs3], fb[g + xs3 + DHW]);
        int basep = 1 + row * XS + x0;
        sub[basep]     = d0;
        sub[basep + 1] = d1;
        sub[basep + 2] = d2;
        sub[basep + 3] = d3;
    }
    // tail: x = 24 per row
    for (int row = tid; row < rows; row += 384) {
        int z  = (int)(((unsigned)row * mz) >> 16);
        int y  = row - z * yn;
        int xs = min(24, xn - 1);
        int g  = gz + z * HW + y * Wc + xs;
        sub[1 + row * XS + 24] = pk_f16(fb[g], fb[g + DHW]);
    }
    __syncthreads();

    if (tid < CELLS) {
        int i   = tid / 49;
        int rem = tid - i * 49;
        int j   = rem / 7;
        int k   = rem - j * 7;
        int4   tzr = *(const int4*)&tzp[2 * i];   // (c0, c1, c0', c1') raw rows
        float4 wzv = *(const float4*)&wzp[2 * i];
        int4   ty  = *(const int4*)&typ[2 * j];
        float4 wyv = *(const float4*)&wyp[2 * j];
        int    xo0 = txo[2 * k], xo1 = txo[2 * k + 1];
        unsigned wh0 = wxh[2 * k], wh1 = wxh[2 * k + 1];

        const unsigned* G = sub + 1;

        // z 3-slot collapse: corners lie in {c0, c0+1, c0+2}.
        int c0z = tzr.x;
        int p1 = tzr.y - c0z;               // {0,1}
        int p2 = tzr.z - c0z;               // {0,1}
        int p3 = tzr.w - c0z;               // {0,1,2}
        float cz0 = wzv.x + (p1 == 0 ? wzv.y : 0.0f)
                  + (p2 == 0 ? wzv.z : 0.0f) + (p3 == 0 ? wzv.w : 0.0f);
        float cz1 = (p1 == 1 ? wzv.y : 0.0f)
                  + (p2 == 1 ? wzv.z : 0.0f) + (p3 == 1 ? wzv.w : 0.0f);
        float cz2 = (p3 == 2 ? wzv.w : 0.0f);
        int zb0 = c0z * zstride;
        int zb1 = min(c0z + 1, zn - 1) * zstride;
        int zb2 = min(c0z + 2, zn - 1) * zstride;

        const int   zbs[3] = {zb0, zb1, zb2};
        const float czs[3] = {cz0, cz1, cz2};
        const int   yo[4] = {ty.x, ty.y, ty.z, ty.w};
        const float wy[4] = {wyv.x, wyv.y, wyv.z, wyv.w};

        float a0 = 0.0f, a1 = 0.0f;
        #pragma unroll
        for (int d = 0; d < 3; ++d) {
            int zb = zbs[d];
            float s0 = 0.0f, s1 = 0.0f;
            #pragma unroll
            for (int yi = 0; yi < 4; ++yi) {
                int base = zb + yo[yi];
                unsigned p0a = G[base + xo0], p0b = G[base + xo0 + 1];
                unsigned p1a = G[base + xo1], p1b = G[base + xo1 + 1];
                unsigned c0p0 = __builtin_amdgcn_perm(p0b, p0a, 0x05040100u);
                unsigned c1p0 = __builtin_amdgcn_perm(p0b, p0a, 0x07060302u);
                unsigned c0p1 = __builtin_amdgcn_perm(p1b, p1a, 0x05040100u);
                unsigned c1p1 = __builtin_amdgcn_perm(p1b, p1a, 0x07060302u);
                float r0 = fdot2(c0p1, wh1, fdot2(c0p0, wh0, 0.0f));
                float r1 = fdot2(c1p1, wh1, fdot2(c1p0, wh0, 0.0f));
                s0 = fmaf(wy[yi], r0, s0);
                s1 = fmaf(wy[yi], r1, s1);
            }
            a0 = fmaf(czs[d], s0, a0);
            a1 = fmaf(czs[d], s1, a1);
        }
        size_t obase = ((size_t)(b * Nc + n) * Cc + c0ch) * CELLS;
        out[obase + tid]         = a0 * 0.125f;
        out[obase + CELLS + tid] = a1 * 0.125f;
    }
}

extern "C" void kernel_launch(void* const* d_in, const int* in_sizes, int n_in,
                              void* d_out, int out_size, void* d_ws, size_t ws_size,
                              hipStream_t stream) {
    const float* feat = (const float*)d_in[0];
    const float* rois = (const float*)d_in[1];
    float* out = (float*)d_out;
    int blocks = Bc * Nc * (Cc / 2);   // 8192
    hipLaunchKernelGGL(roialign3d_v10, dim3(blocks), dim3(384), 0, stream,
                       feat, rois, out);
}

// Round 11
// 42.908 us; speedup vs baseline: 1.4022x; 1.4022x over previous
//
#include <hip/hip_runtime.h>

// ROIAlign3D: features [B=2,C=128,D=16,H=64,W=64] f32, rois [B,N=64,6] f32
// out [B,N,C,7,7,7] f32. SAMPLING_RATIO=2, ALIGNED=true, SPATIAL_SCALE=1.
//
// Round 11: v9 base (48.8us) + masked v10 wins, chunking reverted:
//  - staging is lane-consecutive per-voxel (v9 coalescing: consecutive lanes
//    -> consecutive addresses; v10's 4-chunking tripled TA line-touches).
//  - runtime umulhi magic-div for p->(row,x) and row->(z,y): no rowglob
//    table, no LDS reads in staging. Exact for p<=6250, d>=2.
//  - tight x-stride xnp=xn|1 (not fixed 25): avg box xn~14 -> ~40% less
//    staging work. Pad column staged clamped so all readable slots finite.
//  - single barrier.
constexpr int Bc = 2, Nc = 64, Cc = 128, Dc = 16, Hc = 64, Wc = 64;
constexpr int OD = 7, OH = 7, OW = 7;
constexpr int CELLS = OD * OH * OW;          // 343
constexpr int DHW = Dc * Hc * Wc, HW = Hc * Wc;
constexpr int MAXZ = 10, MAXY = 25, MAXX = 25;
constexpr int SUBSZ = MAXZ * MAXY * (MAXX + 1);   // worst-case rows*xnp

typedef __fp16 h2 __attribute__((ext_vector_type(2)));

__device__ inline unsigned pk_f16(float a, float b) {
    return __builtin_bit_cast(unsigned, __builtin_amdgcn_cvt_pkrtz(a, b));
}

__device__ inline float fdot2(unsigned a, unsigned b, float c) {
#if __has_builtin(__builtin_amdgcn_fdot2)
    return __builtin_amdgcn_fdot2(__builtin_bit_cast(h2, a),
                                  __builtin_bit_cast(h2, b), c, false);
#else
    h2 ha = __builtin_bit_cast(h2, a);
    h2 hb = __builtin_bit_cast(h2, b);
    return fmaf((float)ha.x, (float)hb.x, fmaf((float)ha.y, (float)hb.y, c));
#endif
}

__global__ __launch_bounds__(384) void roialign3d_v11(
    const float* __restrict__ feat, const float* __restrict__ rois,
    float* __restrict__ out)
{
    __shared__ unsigned sub[SUBSZ + 2];       // [0]=front pad, data, end pad
    __shared__ int2     tzp[14], typ[14];     // tzp: RAW z rows (c0,c1)
    __shared__ float2   wzp[14], wyp[14];
    __shared__ int      txo[14];
    __shared__ unsigned wxh[14];              // packed f16 (w_left, w_right)

    const int blk = blockIdx.x;
    const int cp  = blk & 63;
    const int n   = (blk >> 6) & 63;
    const int b   = blk >> 12;
    const int tid = threadIdx.x;

    const float* rp = rois + (size_t)(b * Nc + n) * 6;
    float r1a[3] = {rp[0] - 0.5f, rp[1] - 0.5f, rp[2] - 0.5f};
    float r2a[3] = {rp[3] - 0.5f, rp[4] - 0.5f, rp[5] - 0.5f};
    const int dims[3] = {Dc, Hc, Wc};
    const int maxn[3] = {MAXZ, MAXY, MAXX};

    float bs[3]; int lo[3], ncnt[3];
    #pragma unroll
    for (int a = 0; a < 3; ++a) {
        bs[a] = fmaxf(r2a[a] - r1a[a], 1e-6f) * (1.0f / 7.0f);
        float smin = r1a[a] + 0.25f * bs[a];
        float smax = r1a[a] + 6.75f * bs[a];
        int l = max(0, (int)floorf(smin));
        int h = min(dims[a] - 1, (int)floorf(smax) + 1);
        lo[a] = l;
        ncnt[a] = min(h - l + 1, maxn[a]);    // maxn clamp = memory safety only
    }
    const int zn = ncnt[0], yn = ncnt[1], xn = ncnt[2];
    const int xnp = xn | 1;                   // odd stride (>= xn, <= 26)
    const int rows = zn * yn;
    const int zstride = yn * xnp;

    // Axis tables (42 threads).
    if (tid < 42) {
        int a = tid / 14, m = tid - a * 14;
        float v = r1a[a] + ((float)m + 0.5f) * 0.5f * bs[a];
        float f = floorf(v);
        float l = v - f;
        int i0 = (int)f;
        int d  = dims[a];
        float w0 = (i0 >= 0 && i0 < d) ? 1.0f - l : 0.0f;
        float w1 = (i0 + 1 < d) ? l : 0.0f;
        if (a == 0) {
            int c0 = min(max(i0 - lo[0], 0), zn - 1);
            int c1 = min(max(i0 + 1 - lo[0], 0), zn - 1);
            tzp[m] = make_int2(c0, c1);              // RAW rows
            wzp[m] = make_float2(w0, w1);
        } else if (a == 1) {
            int c0 = min(max(i0 - lo[1], 0), yn - 1);
            int c1 = min(max(i0 + 1 - lo[1], 0), yn - 1);
            typ[m] = make_int2(c0 * xnp, c1 * xnp);
            wyp[m] = make_float2(w0, w1);
        } else {
            // pair trick: corners are (c0, c0+1); c0 in [-1, xn-1].
            int c0 = min(max(i0 - lo[2], -1), xn - 1);
            txo[m] = c0;
            wxh[m] = pk_f16(w0, w1);
        }
    }
    if (tid == 64) sub[0] = 0;                        // front pad (c0 = -1)
    if (tid == 65) sub[1 + rows * xnp] = 0;           // end pad (last row +xn)

    // ---- Stage subvolume (fp16x2), lane-consecutive, magic-div indexing. ----
    const int c0ch = cp * 2;
    const float* fb = feat + ((size_t)b * Cc + c0ch) * DHW;
    const unsigned m32x = 0xFFFFFFFFu / (unsigned)xnp + 1u;   // d>=3 (odd>=3)
    const unsigned m32y = 0xFFFFFFFFu / (unsigned)yn + 1u;    // yn>=2
    const int gz = lo[0] * HW + lo[1] * Wc + lo[2];
    const int total = rows * xnp;
    for (int p = tid; p < total; p += 384) {
        int row = (int)__umulhi((unsigned)p, m32x);   // p / xnp
        int x   = p - row * xnp;
        int xs  = min(x, xn - 1);
        int z   = (int)__umulhi((unsigned)row, m32y); // row / yn
        int y   = row - z * yn;
        int g   = gz + (z << 12) + (y << 6) + xs;     // HW=4096, Wc=64
        sub[1 + p] = pk_f16(fb[g], fb[g + DHW]);
    }
    __syncthreads();

    if (tid < CELLS) {
        int i   = tid / 49;
        int rem = tid - i * 49;
        int j   = rem / 7;
        int k   = rem - j * 7;
        int4   tzr = *(const int4*)&tzp[2 * i];   // (c0, c1, c0', c1') raw rows
        float4 wzv = *(const float4*)&wzp[2 * i];
        int4   ty  = *(const int4*)&typ[2 * j];
        float4 wyv = *(const float4*)&wyp[2 * j];
        int    xo0 = txo[2 * k], xo1 = txo[2 * k + 1];
        unsigned wh0 = wxh[2 * k], wh1 = wxh[2 * k + 1];

        const unsigned* G = sub + 1;

        // z 3-slot collapse: corners lie in {c0, c0+1, c0+2}.
        int c0z = tzr.x;
        int p1 = tzr.y - c0z;               // {0,1}
        int p2 = tzr.z - c0z;               // {0,1}
        int p3 = tzr.w - c0z;               // {0,1,2}
        float cz0 = wzv.x + (p1 == 0 ? wzv.y : 0.0f)
                  + (p2 == 0 ? wzv.z : 0.0f) + (p3 == 0 ? wzv.w : 0.0f);
        float cz1 = (p1 == 1 ? wzv.y : 0.0f)
                  + (p2 == 1 ? wzv.z : 0.0f) + (p3 == 1 ? wzv.w : 0.0f);
        float cz2 = (p3 == 2 ? wzv.w : 0.0f);
        // weight-0 slots clamp to a staged (finite) row.
        int zb0 = c0z * zstride;
        int zb1 = min(c0z + 1, zn - 1) * zstride;
        int zb2 = min(c0z + 2, zn - 1) * zstride;

        const int   zbs[3] = {zb0, zb1, zb2};
        const float czs[3] = {cz0, cz1, cz2};
        const int   yo[4] = {ty.x, ty.y, ty.z, ty.w};
        const float wy[4] = {wyv.x, wyv.y, wyv.z, wyv.w};

        float a0 = 0.0f, a1 = 0.0f;
        #pragma unroll
        for (int d = 0; d < 3; ++d) {
            int zb = zbs[d];
            float s0 = 0.0f, s1 = 0.0f;
            #pragma unroll
            for (int yi = 0; yi < 4; ++yi) {
                int base = zb + yo[yi];
                unsigned p0a = G[base + xo0], p0b = G[base + xo0 + 1];
                unsigned p1a = G[base + xo1], p1b = G[base + xo1 + 1];
                unsigned c0p0 = __builtin_amdgcn_perm(p0b, p0a, 0x05040100u);
                unsigned c1p0 = __builtin_amdgcn_perm(p0b, p0a, 0x07060302u);
                unsigned c0p1 = __builtin_amdgcn_perm(p1b, p1a, 0x05040100u);
                unsigned c1p1 = __builtin_amdgcn_perm(p1b, p1a, 0x07060302u);
                float r0 = fdot2(c0p1, wh1, fdot2(c0p0, wh0, 0.0f));
                float r1 = fdot2(c1p1, wh1, fdot2(c1p0, wh0, 0.0f));
                s0 = fmaf(wy[yi], r0, s0);
                s1 = fmaf(wy[yi], r1, s1);
            }
            a0 = fmaf(czs[d], s0, a0);
            a1 = fmaf(czs[d], s1, a1);
        }
        size_t obase = ((size_t)(b * Nc + n) * Cc + c0ch) * CELLS;
        out[obase + tid]         = a0 * 0.125f;
        out[obase + CELLS + tid] = a1 * 0.125f;
    }
}

extern "C" void kernel_launch(void* const* d_in, const int* in_sizes, int n_in,
                              void* d_out, int out_size, void* d_ws, size_t ws_size,
                              hipStream_t stream) {
    const float* feat = (const float*)d_in[0];
    const float* rois = (const float*)d_in[1];
    float* out = (float*)d_out;
    int blocks = Bc * Nc * (Cc / 2);   // 8192
    hipLaunchKernelGGL(roialign3d_v11, dim3(blocks), dim3(384), 0, stream,
                       feat, rois, out);
}